// Round 1
// baseline (6318.114 us; speedup 1.0000x reference)
//
#include <hip/hip_runtime.h>

#define ALPHA 0.35f
#define BQ 1024
#define DIM 384
#define NC 131072
#define K 16

#define TB 64               // queries per block (main kernel)
#define CHUNK 1024          // candidates per block
#define SUBC 32             // candidates per subtile (64 interleaved rows)
#define KD 32               // k-chunk
#define NKC (DIM / KD)      // 12
#define NSUB (CHUNK / SUBC) // 32
#define NCHUNKS (NC / CHUNK) // 128
#define NQT (BQ / TB)        // 16
#define LSTR 68              // padded LDS leading stride (16B-aligned, conflict-free)

// ---------------- kernel 1: normalize queries ----------------
__global__ __launch_bounds__(384) void qnorm_kernel(const float* __restrict__ q,
                                                    float* __restrict__ qn) {
  const int b = blockIdx.x;   // 1024 blocks
  const int t = threadIdx.x;  // 384 threads = 6 waves
  float v = q[b * DIM + t];
  float s = v * v;
  #pragma unroll
  for (int m = 32; m; m >>= 1) s += __shfl_xor(s, m);
  __shared__ float ws[6];
  if ((t & 63) == 0) ws[t >> 6] = s;
  __syncthreads();
  float tot = ws[0] + ws[1] + ws[2] + ws[3] + ws[4] + ws[5];
  float n = fmaxf(sqrtf(tot), 1e-12f);
  qn[b * DIM + t] = v / n;
}

// ---------------- kernel 2: inverse row norms of e and d ----------------
__global__ __launch_bounds__(256) void rownorm_kernel(const float* __restrict__ e,
                                                      const float* __restrict__ d,
                                                      float* __restrict__ inv_e,
                                                      float* __restrict__ inv_d) {
  const int wid = threadIdx.x >> 6, lane = threadIdx.x & 63;
  const int row = blockIdx.x * 4 + wid;  // grid.x = NC/4
  const float* src = blockIdx.y ? d : e;
  const float* p = src + (size_t)row * DIM;
  float s = 0.f;
  #pragma unroll
  for (int j = 0; j < 6; j++) { float v = p[j * 64 + lane]; s += v * v; }
  #pragma unroll
  for (int m = 32; m; m >>= 1) s += __shfl_xor(s, m);
  if (lane == 0) {
    float n = fmaxf(sqrtf(s), 1e-12f);
    (blockIdx.y ? inv_d : inv_e)[row] = 1.0f / n;
  }
}

// ---------------- kernel 3: fused score GEMM + per-chunk top-16 ----------------
// grid: (NQT, NCHUNKS), block: 256.
// Interleaved "combined rows": crow 2i -> e_i, crow 2i+1 -> d_i.
__global__ __launch_bounds__(256) void score_topk_kernel(
    const float* __restrict__ e, const float* __restrict__ d,
    const float* __restrict__ qn, const float* __restrict__ inv_e,
    const float* __restrict__ inv_d, float* __restrict__ cand_vals,
    int* __restrict__ cand_idx) {
  __shared__ float q_s[KD * LSTR];   // k-major [k][qrow]
  __shared__ float c_s[KD * LSTR];   // k-major [k][crow]
  __shared__ float sc_s[TB * 33];    // score tile [q][cand_local]
  __shared__ float tv_s[TB * 17];    // running top-16 values
  __shared__ int   ti_s[TB * 17];    // running top-16 indices

  const int t = threadIdx.x;
  const int q0 = blockIdx.x * TB;
  const int cand0 = blockIdx.y * CHUNK;

  // staging mapping: 4 threads per row, contiguous 64B per 4 lanes
  const int sr = t >> 2;            // row 0..63
  const int sk = (t & 3) * 4;       // k offsets sk..sk+3 and sk+16..sk+19

  // compute mapping: 16x16 thread grid, 4x4 micro-tile
  const int tx = t & 15, ty = t >> 4;

  float minv = -INFINITY;
  int   minp = 0;
  if (t < TB) {
    #pragma unroll
    for (int i = 0; i < K; i++) { tv_s[t * 17 + i] = -INFINITY; ti_s[t * 17 + i] = 0x7fffffff; }
  }

  const float* qrow = qn + (size_t)(q0 + sr) * DIM;
  const float* csrc = (sr & 1) ? d : e;

  for (int sub = 0; sub < NSUB; sub++) {
    const int cbase = cand0 + sub * SUBC;
    const float* crow = csrc + (size_t)(cbase + (sr >> 1)) * DIM;
    float acc[4][4] = {{0.f}};

    for (int kc = 0; kc < NKC; kc++) {
      __syncthreads();  // previous readers done with q_s/c_s
      const int kb = kc * KD;
      float4 qa = *reinterpret_cast<const float4*>(qrow + kb + sk);
      float4 qb = *reinterpret_cast<const float4*>(qrow + kb + sk + 16);
      float4 ca = *reinterpret_cast<const float4*>(crow + kb + sk);
      float4 cb = *reinterpret_cast<const float4*>(crow + kb + sk + 16);
      q_s[(sk + 0) * LSTR + sr] = qa.x;  q_s[(sk + 1) * LSTR + sr] = qa.y;
      q_s[(sk + 2) * LSTR + sr] = qa.z;  q_s[(sk + 3) * LSTR + sr] = qa.w;
      q_s[(sk + 16) * LSTR + sr] = qb.x; q_s[(sk + 17) * LSTR + sr] = qb.y;
      q_s[(sk + 18) * LSTR + sr] = qb.z; q_s[(sk + 19) * LSTR + sr] = qb.w;
      c_s[(sk + 0) * LSTR + sr] = ca.x;  c_s[(sk + 1) * LSTR + sr] = ca.y;
      c_s[(sk + 2) * LSTR + sr] = ca.z;  c_s[(sk + 3) * LSTR + sr] = ca.w;
      c_s[(sk + 16) * LSTR + sr] = cb.x; c_s[(sk + 17) * LSTR + sr] = cb.y;
      c_s[(sk + 18) * LSTR + sr] = cb.z; c_s[(sk + 19) * LSTR + sr] = cb.w;
      __syncthreads();
      #pragma unroll
      for (int k = 0; k < KD; k++) {
        float4 qv = *reinterpret_cast<const float4*>(&q_s[k * LSTR + ty * 4]);
        float4 cv = *reinterpret_cast<const float4*>(&c_s[k * LSTR + tx * 4]);
        acc[0][0] += qv.x * cv.x; acc[0][1] += qv.x * cv.y; acc[0][2] += qv.x * cv.z; acc[0][3] += qv.x * cv.w;
        acc[1][0] += qv.y * cv.x; acc[1][1] += qv.y * cv.y; acc[1][2] += qv.y * cv.z; acc[1][3] += qv.y * cv.w;
        acc[2][0] += qv.z * cv.x; acc[2][1] += qv.z * cv.y; acc[2][2] += qv.z * cv.z; acc[2][3] += qv.z * cv.w;
        acc[3][0] += qv.w * cv.x; acc[3][1] += qv.w * cv.y; acc[3][2] += qv.w * cv.z; acc[3][3] += qv.w * cv.w;
      }
    }
    __syncthreads();
    // epilogue: combine primal+dual, write 64x32 score tile
    {
      const int c0 = cbase + tx * 2;
      const float ie0 = inv_e[c0], id0 = inv_d[c0];
      const float ie1 = inv_e[c0 + 1], id1 = inv_d[c0 + 1];
      #pragma unroll
      for (int i = 0; i < 4; i++) {
        float s0 = acc[i][0] * ie0 + ALPHA * fmaxf(acc[i][1] * id0, 0.f);
        float s1 = acc[i][2] * ie1 + ALPHA * fmaxf(acc[i][3] * id1, 0.f);
        sc_s[(ty * 4 + i) * 33 + tx * 2]     = s0;
        sc_s[(ty * 4 + i) * 33 + tx * 2 + 1] = s1;
      }
    }
    __syncthreads();
    // running top-16 update; ascending index order => strict '>' keeps lowest index on ties
    if (t < TB) {
      for (int c = 0; c < SUBC; c++) {
        float s = sc_s[t * 33 + c];
        if (s > minv) {
          tv_s[t * 17 + minp] = s;
          ti_s[t * 17 + minp] = cbase + c;
          float mv = INFINITY; int mp = 0, mi = -1;
          #pragma unroll
          for (int i = 0; i < K; i++) {
            float v = tv_s[t * 17 + i]; int ix = ti_s[t * 17 + i];
            if (v < mv || (v == mv && ix > mi)) { mv = v; mp = i; mi = ix; }
          }
          minv = mv; minp = mp;
        }
      }
    }
  }
  __syncthreads();
  if (t < TB) {
    const int qg = q0 + t;
    float* vdst = cand_vals + ((size_t)blockIdx.y * BQ + qg) * K;
    int*   idst = cand_idx  + ((size_t)blockIdx.y * BQ + qg) * K;
    #pragma unroll
    for (int i = 0; i < K; i++) { vdst[i] = tv_s[t * 17 + i]; idst[i] = ti_s[t * 17 + i]; }
  }
}

// ---------------- kernel 4: merge 128 chunk-lists -> global top-16 ----------------
#define NCM (NCHUNKS * K)  // 2048 candidates per query
__global__ __launch_bounds__(256) void merge_kernel(const float* __restrict__ cand_vals,
                                                    const int* __restrict__ cand_idx,
                                                    float* __restrict__ out) {
  __shared__ float mv[NCM];
  __shared__ int   mi[NCM];
  __shared__ float rv[256];
  __shared__ int   ri[256];
  __shared__ int   rp[256];
  const int q = blockIdx.x, t = threadIdx.x;
  #pragma unroll
  for (int j = 0; j < NCM / 256; j++) {
    int el = t + 256 * j;
    int chunk = el >> 4, slot = el & 15;
    mv[el] = cand_vals[((size_t)chunk * BQ + q) * K + slot];
    mi[el] = cand_idx[((size_t)chunk * BQ + q) * K + slot];
  }
  __syncthreads();
  for (int pass = 0; pass < K; pass++) {
    float bv = -INFINITY; int bi = 0x7fffffff, bp = 0;
    #pragma unroll
    for (int j = 0; j < NCM / 256; j++) {
      int el = t + 256 * j;
      float v = mv[el]; int ix = mi[el];
      if (v > bv || (v == bv && ix < bi)) { bv = v; bi = ix; bp = el; }
    }
    rv[t] = bv; ri[t] = bi; rp[t] = bp;
    __syncthreads();
    for (int s = 128; s > 0; s >>= 1) {
      if (t < s) {
        float v = rv[t + s]; int ix = ri[t + s];
        if (v > rv[t] || (v == rv[t] && ix < ri[t])) { rv[t] = v; ri[t] = ix; rp[t] = rp[t + s]; }
      }
      __syncthreads();
    }
    if (t == 0) {
      out[q * K + pass] = rv[0];                     // top values  [1024][16]
      out[BQ * K + q * K + pass] = (float)ri[0];     // indices as float [1024][16]
      mv[rp[0]] = -INFINITY;
      mi[rp[0]] = 0x7fffffff;
    }
    __syncthreads();
  }
}

extern "C" void kernel_launch(void* const* d_in, const int* in_sizes, int n_in,
                              void* d_out, int out_size, void* d_ws, size_t ws_size,
                              hipStream_t stream) {
  const float* q = (const float*)d_in[0];
  const float* e = (const float*)d_in[1];
  const float* d = (const float*)d_in[2];
  // top_k input (d_in[3]) is always 16 per the reference default.

  float* ws = (float*)d_ws;
  float* qn       = ws;                         // 1024*384
  float* inv_e    = qn + BQ * DIM;              // 131072
  float* inv_d    = inv_e + NC;                 // 131072
  float* cand_vals = inv_d + NC;                // 128*1024*16
  int*   cand_idx  = (int*)(cand_vals + (size_t)NCHUNKS * BQ * K);
  float* out = (float*)d_out;

  qnorm_kernel<<<BQ, 384, 0, stream>>>(q, qn);
  rownorm_kernel<<<dim3(NC / 4, 2), 256, 0, stream>>>(e, d, inv_e, inv_d);
  score_topk_kernel<<<dim3(NQT, NCHUNKS), 256, 0, stream>>>(e, d, qn, inv_e, inv_d,
                                                            cand_vals, cand_idx);
  merge_kernel<<<BQ, 256, 0, stream>>>(cand_vals, cand_idx, out);
}

// Round 2
// 3408.258 us; speedup vs baseline: 1.8538x; 1.8538x over previous
//
#include <hip/hip_runtime.h>

#define ALPHA 0.35f
#define BQ 1024
#define DIM 384
#define NC 131072
#define TOPK 16

#define QT 128              // queries per block
#define NQT (BQ / QT)       // 8
#define CH 512              // candidates per chunk
#define NCH (NC / CH)       // 256
#define SUBC 64             // candidates per subtile (128 interleaved crows)
#define NSUB (CH / SUBC)    // 8
#define BK 64               // bf16 k-slice
#define NKI (DIM / BK)      // 6
#define ASTR 72             // LDS row stride (bf16 elems): 144B, 16B-aligned, 2-way max

typedef short bf16x8 __attribute__((ext_vector_type(8)));
typedef float floatx4 __attribute__((ext_vector_type(4)));

// pack 2 fp32 -> 2 bf16 (truncation) in one v_perm_b32.
// low16 = a.hi16 (k even), high16 = b.hi16 (k odd).
static __device__ __forceinline__ unsigned pk2(float a, float b) {
  unsigned ua = __builtin_bit_cast(unsigned, a);
  unsigned ub = __builtin_bit_cast(unsigned, b);
  return __builtin_amdgcn_perm(ub, ua, 0x07060302u);
}

// stage 32 fp32 -> 32 bf16 (64B) into LDS
static __device__ __forceinline__ void stage_half(const float* __restrict__ src,
                                                  ushort* __restrict__ dst) {
  const float4* p = reinterpret_cast<const float4*>(src);
  float4 v0 = p[0], v1 = p[1], v2 = p[2], v3 = p[3];
  float4 v4 = p[4], v5 = p[5], v6 = p[6], v7 = p[7];
  uint4* q = reinterpret_cast<uint4*>(dst);
  q[0] = make_uint4(pk2(v0.x, v0.y), pk2(v0.z, v0.w), pk2(v1.x, v1.y), pk2(v1.z, v1.w));
  q[1] = make_uint4(pk2(v2.x, v2.y), pk2(v2.z, v2.w), pk2(v3.x, v3.y), pk2(v3.z, v3.w));
  q[2] = make_uint4(pk2(v4.x, v4.y), pk2(v4.z, v4.w), pk2(v5.x, v5.y), pk2(v5.z, v5.w));
  q[3] = make_uint4(pk2(v6.x, v6.y), pk2(v6.z, v6.w), pk2(v7.x, v7.y), pk2(v7.z, v7.w));
}

// ---------------- kernel 1: normalize queries (fp32, exact ref math) ----------------
__global__ __launch_bounds__(384) void qnorm_kernel(const float* __restrict__ q,
                                                    float* __restrict__ qn) {
  const int b = blockIdx.x;
  const int t = threadIdx.x;
  float v = q[b * DIM + t];
  float s = v * v;
  #pragma unroll
  for (int m = 32; m; m >>= 1) s += __shfl_xor(s, m);
  __shared__ float ws[6];
  if ((t & 63) == 0) ws[t >> 6] = s;
  __syncthreads();
  float tot = ws[0] + ws[1] + ws[2] + ws[3] + ws[4] + ws[5];
  float n = fmaxf(sqrtf(tot), 1e-12f);
  qn[b * DIM + t] = v / n;
}

// ---------------- kernel 2: inverse row norms of e and d (exact ref math) ----------------
__global__ __launch_bounds__(256) void rownorm_kernel(const float* __restrict__ e,
                                                      const float* __restrict__ d,
                                                      float* __restrict__ inv_e,
                                                      float* __restrict__ inv_d) {
  const int wid = threadIdx.x >> 6, lane = threadIdx.x & 63;
  const int row = blockIdx.x * 4 + wid;
  const float* src = blockIdx.y ? d : e;
  const float* p = src + (size_t)row * DIM;
  float s = 0.f;
  #pragma unroll
  for (int j = 0; j < 6; j++) { float v = p[j * 64 + lane]; s += v * v; }
  #pragma unroll
  for (int m = 32; m; m >>= 1) s += __shfl_xor(s, m);
  if (lane == 0) {
    float n = fmaxf(sqrtf(s), 1e-12f);
    (blockIdx.y ? inv_d : inv_e)[row] = 1.0f / n;
  }
}

// ---------------- kernel 3: bf16 MFMA approx scores + per-chunk top-16 ----------------
// grid (NCH, NQT), block 256. crow 2i -> e_i, crow 2i+1 -> d_i.
__global__ __launch_bounds__(256, 3) void score_kernel(
    const float* __restrict__ e, const float* __restrict__ d,
    const float* __restrict__ qn, const float* __restrict__ inv_e,
    const float* __restrict__ inv_d, float* __restrict__ cand_vals,
    int* __restrict__ cand_idx) {
  // LDS: [A 128x72 bf16 | B 128x72 bf16] (36864B, aliased by scores 128x65 fp32)
  //      + heap vals 128x16 fp32 + heap idx 128x16 int  => 53248B total, 3 blocks/CU
  __shared__ __align__(16) char smem[53248];
  ushort* As = (ushort*)smem;
  ushort* Bs = (ushort*)(smem + 18432);
  float*  sc = (float*)smem;                 // stride 65
  float*  tv = (float*)(smem + 36864);
  int*    ti = (int*)(smem + 45056);

  const int t = threadIdx.x;
  const int ch = blockIdx.x, qt = blockIdx.y;
  const int q0 = qt * QT;
  const int c0 = ch * CH;
  const int lane = t & 63, wave = t >> 6;
  const int wy = wave >> 1, wx = wave & 1;
  const int mrow = lane & 15, quad = lane >> 4;

  // staging mapping: thread t stages half-row (32 floats) of A row srow and B crow srow
  const int srow = t >> 1, shalf = t & 1;
  const float* qsrc = qn + (size_t)(q0 + srow) * DIM + shalf * 32;
  const float* bsel = (srow & 1) ? d : e;

  float minv = -INFINITY; int minp = 0;
  if (t < QT) {
    #pragma unroll
    for (int i = 0; i < TOPK; i++) { tv[t * 16 + i] = -INFINITY; ti[t * 16 + i] = 0x7fffffff; }
  }

  for (int sub = 0; sub < NSUB; sub++) {
    const int cb = c0 + sub * SUBC;
    const float* bsrc = bsel + (size_t)(cb + (srow >> 1)) * DIM + shalf * 32;
    floatx4 acc[4][4];
    #pragma unroll
    for (int i = 0; i < 4; i++)
      #pragma unroll
      for (int j = 0; j < 4; j++) acc[i][j] = (floatx4)0.f;

    for (int ki = 0; ki < NKI; ki++) {
      const int kb = ki * BK;
      __syncthreads();  // tiles/scores free
      stage_half(qsrc + kb, &As[srow * ASTR + shalf * 32]);
      stage_half(bsrc + kb, &Bs[srow * ASTR + shalf * 32]);
      __syncthreads();
      #pragma unroll
      for (int ks = 0; ks < 2; ks++) {
        bf16x8 af[4], bf[4];
        #pragma unroll
        for (int i = 0; i < 4; i++)
          af[i] = *reinterpret_cast<const bf16x8*>(&As[(wy * 64 + i * 16 + mrow) * ASTR + ks * 32 + quad * 8]);
        #pragma unroll
        for (int j = 0; j < 4; j++)
          bf[j] = *reinterpret_cast<const bf16x8*>(&Bs[(wx * 64 + j * 16 + mrow) * ASTR + ks * 32 + quad * 8]);
        #pragma unroll
        for (int i = 0; i < 4; i++)
          #pragma unroll
          for (int j = 0; j < 4; j++)
            acc[i][j] = __builtin_amdgcn_mfma_f32_16x16x32_bf16(af[i], bf[j], acc[i][j], 0, 0, 0);
      }
    }
    __syncthreads();  // MFMA frag reads done -> scores may overwrite tiles
    // epilogue: C layout col=lane&15 (crow), row=quad*4+reg (q). even col=primal, odd=dual.
    {
      const int col = lane & 15;
      #pragma unroll
      for (int j = 0; j < 4; j++) {
        const int candl = wx * 32 + j * 8 + (col >> 1);
        const int cg = cb + candl;
        const float ie = inv_e[cg];
        const float id = inv_d[cg];
        #pragma unroll
        for (int i = 0; i < 4; i++) {
          #pragma unroll
          for (int r = 0; r < 4; r++) {
            float v = acc[i][j][r];
            float p = __shfl_xor(v, 1);
            if (!(col & 1)) {
              float s = v * ie + ALPHA * fmaxf(p * id, 0.f);
              sc[(wy * 64 + i * 16 + quad * 4 + r) * 65 + candl] = s;
            }
          }
        }
      }
    }
    __syncthreads();
    // running top-16; ascending index scan + strict '>' => lowest index on ties
    if (t < QT) {
      for (int c = 0; c < SUBC; c++) {
        float s = sc[t * 65 + c];
        if (s > minv) {
          tv[t * 16 + minp] = s;
          ti[t * 16 + minp] = cb + c;
          float mv = INFINITY; int mp = 0, mi = -1;
          #pragma unroll
          for (int i = 0; i < TOPK; i++) {
            float v = tv[t * 16 + i]; int ix = ti[t * 16 + i];
            if (v < mv || (v == mv && ix > mi)) { mv = v; mp = i; mi = ix; }
          }
          minv = mv; minp = mp;
        }
      }
    }
    // next iteration's first __syncthreads protects sc before restaging
  }
  __syncthreads();
  if (t < QT) {
    const int qg = q0 + t;
    const size_t base = ((size_t)ch * BQ + qg) * TOPK;
    #pragma unroll
    for (int i = 0; i < TOPK; i++) { cand_vals[base + i] = tv[t * 16 + i]; cand_idx[base + i] = ti[t * 16 + i]; }
  }
}

// ---------------- kernel 4: merge 256 chunk-lists -> approx top-32 -> fp32 rescore -> top-16 ----------------
#define POOL (NCH * TOPK)   // 4096
#define MSEL 32
__global__ __launch_bounds__(256) void merge_rescore_kernel(
    const float* __restrict__ cand_vals, const int* __restrict__ cand_idx,
    const float* __restrict__ qn, const float* __restrict__ e,
    const float* __restrict__ d, const float* __restrict__ inv_e,
    const float* __restrict__ inv_d, float* __restrict__ out) {
  __shared__ float mv[POOL];
  __shared__ int   mi[POOL];
  __shared__ float qf[DIM];
  __shared__ float wrv[4]; __shared__ int wri[4]; __shared__ int wrp[4];
  __shared__ float selv[MSEL]; __shared__ int seli[MSEL];
  __shared__ float fv[MSEL]; __shared__ int fi[MSEL];

  const int q = blockIdx.x, t = threadIdx.x;
  const int lane = t & 63, wave = t >> 6;

  #pragma unroll
  for (int j = 0; j < POOL / 256; j++) {
    int el = t + 256 * j;
    mv[el] = cand_vals[((size_t)(el >> 4) * BQ + q) * TOPK + (el & 15)];
    mi[el] = cand_idx[((size_t)(el >> 4) * BQ + q) * TOPK + (el & 15)];
  }
  if (t < 128) { qf[t] = qn[q * DIM + t]; qf[t + 128] = qn[q * DIM + t + 128]; qf[t + 256] = qn[q * DIM + t + 256]; }
  __syncthreads();

  // select approx top-32 (value desc, index asc)
  for (int pass = 0; pass < MSEL; pass++) {
    float bv = -INFINITY; int bi = 0x7fffffff, bp = 0;
    #pragma unroll
    for (int j = 0; j < POOL / 256; j++) {
      int el = t + 256 * j;
      float v = mv[el]; int ix = mi[el];
      if (v > bv || (v == bv && ix < bi)) { bv = v; bi = ix; bp = el; }
    }
    #pragma unroll
    for (int off = 1; off < 64; off <<= 1) {
      float ov = __shfl_xor(bv, off); int oi = __shfl_xor(bi, off); int op = __shfl_xor(bp, off);
      if (ov > bv || (ov == bv && oi < bi)) { bv = ov; bi = oi; bp = op; }
    }
    if (lane == 0) { wrv[wave] = bv; wri[wave] = bi; wrp[wave] = bp; }
    __syncthreads();
    if (t == 0) {
      float xv = wrv[0]; int xi = wri[0], xp = wrp[0];
      #pragma unroll
      for (int w = 1; w < 4; w++) {
        if (wrv[w] > xv || (wrv[w] == xv && wri[w] < xi)) { xv = wrv[w]; xi = wri[w]; xp = wrp[w]; }
      }
      selv[pass] = xv; seli[pass] = xi;
      mv[xp] = -INFINITY; mi[xp] = 0x7fffffff;
    }
    __syncthreads();
  }

  // exact fp32 rescore of the 32 candidates (same math as reference)
  for (int c = wave; c < MSEL; c += 4) {
    int idx = seli[c];
    const float* er = e + (size_t)idx * DIM;
    const float* dr = d + (size_t)idx * DIM;
    float se = 0.f, sd = 0.f;
    #pragma unroll
    for (int j = 0; j < 6; j++) {
      float qv = qf[j * 64 + lane];
      se += qv * er[j * 64 + lane];
      sd += qv * dr[j * 64 + lane];
    }
    #pragma unroll
    for (int off = 32; off; off >>= 1) { se += __shfl_xor(se, off); sd += __shfl_xor(sd, off); }
    if (lane == 0) {
      fv[c] = se * inv_e[idx] + ALPHA * fmaxf(sd * inv_d[idx], 0.f);
      fi[c] = idx;
    }
  }
  __syncthreads();

  // final exact top-16 (value desc, index asc), serial on t==0
  if (t == 0) {
    unsigned used = 0u;
    for (int p = 0; p < TOPK; p++) {
      float bv = -INFINITY; int bi = 0x7fffffff, bp = 0;
      for (int c = 0; c < MSEL; c++) {
        if (used & (1u << c)) continue;
        float v = fv[c]; int ix = fi[c];
        if (v > bv || (v == bv && ix < bi)) { bv = v; bi = ix; bp = c; }
      }
      used |= (1u << bp);
      out[q * TOPK + p] = bv;
      out[BQ * TOPK + q * TOPK + p] = (float)bi;
    }
  }
}

extern "C" void kernel_launch(void* const* d_in, const int* in_sizes, int n_in,
                              void* d_out, int out_size, void* d_ws, size_t ws_size,
                              hipStream_t stream) {
  const float* q = (const float*)d_in[0];
  const float* e = (const float*)d_in[1];
  const float* d = (const float*)d_in[2];

  float* ws = (float*)d_ws;
  float* qn        = ws;                                   // 1024*384
  float* inv_e     = qn + BQ * DIM;                        // 131072
  float* inv_d     = inv_e + NC;                           // 131072
  float* cand_vals = inv_d + NC;                           // 256*1024*16
  int*   cand_idx  = (int*)(cand_vals + (size_t)NCH * BQ * TOPK);
  float* out = (float*)d_out;

  qnorm_kernel<<<BQ, 384, 0, stream>>>(q, qn);
  rownorm_kernel<<<dim3(NC / 4, 2), 256, 0, stream>>>(e, d, inv_e, inv_d);
  score_kernel<<<dim3(NCH, NQT), 256, 0, stream>>>(e, d, qn, inv_e, inv_d, cand_vals, cand_idx);
  merge_rescore_kernel<<<BQ, 256, 0, stream>>>(cand_vals, cand_idx, qn, e, d, inv_e, inv_d, out);
}